// Round 1
// baseline (1502.233 us; speedup 1.0000x reference)
//
#include <hip/hip_runtime.h>

#define NN 50000
#define NE 320000
#define FF 256

#define BM 64
#define BK 32
#define APAD 68   // padded LDS row length (words) for transposed A tile; %4==0 for float4 reads

// ---------------- degree ----------------
__global__ void k_deg(const int* __restrict__ ei, float* __restrict__ deg) {
    int e = blockIdx.x * blockDim.x + threadIdx.x;
    if (e < NE) atomicAdd(&deg[ei[NE + e]], 1.0f);
}

__global__ void k_dinv(const float* __restrict__ deg, float* __restrict__ dinv) {
    int n = blockIdx.x * blockDim.x + threadIdx.x;
    if (n < NN) {
        float d = deg[n];
        dinv[n] = d > 0.f ? rsqrtf(d) : 0.f;
    }
}

// ---------------- edge scatter: y[dst] += dinv[src]*dinv[dst] * x[src] ----------------
// one wave (64 lanes) per edge; lane handles 4 contiguous floats (float4 gather)
__global__ void k_scatter(const int* __restrict__ ei, const float* __restrict__ x,
                          const float* __restrict__ dinv, float* __restrict__ y) {
    int gtid = blockIdx.x * blockDim.x + threadIdx.x;
    int wid  = gtid >> 6;
    if (wid >= NE) return;
    int lane = threadIdx.x & 63;
    int src = ei[wid];
    int dst = ei[NE + wid];
    float w = dinv[src] * dinv[dst];
    const float4 v = *reinterpret_cast<const float4*>(&x[(size_t)src * FF + lane * 4]);
    float* yp = &y[(size_t)dst * FF + lane * 4];
    atomicAdd(yp + 0, v.x * w);
    atomicAdd(yp + 1, v.y * w);
    atomicAdd(yp + 2, v.z * w);
    atomicAdd(yp + 3, v.w * w);
}

// ---------------- fused GEMM + epilogue ----------------
// Computes, per 64-row tile, ALL 512 output columns (k=0/1 x 256 g) so that
// y may alias d_out (each row is read/written by exactly one block).
// c_k[n,g] = sum_f y[n,f]*Wi[k,f,g] + sum_f x[n,f]*Wr[k,f,g]
// out[n,g] = x[n,g] + relu( 0.5*( relu(c_0+b0) + relu(c_1+b1) ) )
__global__ __launch_bounds__(512, 4)
void k_gemm(const float* __restrict__ x, const float* __restrict__ y,
            const float* __restrict__ wi, const float* __restrict__ wr,
            const float* __restrict__ bias, float* __restrict__ out) {
    __shared__ float As[BK * APAD];   // transposed: As[f][row]
    __shared__ float Bs[BK * 512];    // Bs[f][col], col = k*256+g

    const int tid = threadIdx.x;
    const int tx = tid & 31;          // 32 col groups
    const int ty = tid >> 5;          // 16 row groups
    const int row0 = blockIdx.x * BM;

    float acc[4][4][4];               // [row i][quadrant j][c] ; col = j*128 + tx*4 + c
    #pragma unroll
    for (int i = 0; i < 4; ++i)
        #pragma unroll
        for (int j = 0; j < 4; ++j)
            #pragma unroll
            for (int c = 0; c < 4; ++c) acc[i][j][c] = 0.f;

    for (int p = 0; p < 2; ++p) {
        const float* A = p ? x : y;
        const float* W = p ? wr : wi;
        for (int f0 = 0; f0 < FF; f0 += BK) {
            // ---- stage A (64 rows x 32 f), one float4 per thread, store transposed
            {
                int r  = tid >> 3;       // 0..63
                int c4 = tid & 7;        // 0..7
                int grow = row0 + r;
                float4 v = make_float4(0.f, 0.f, 0.f, 0.f);
                if (grow < NN)
                    v = *reinterpret_cast<const float4*>(&A[(size_t)grow * FF + f0 + c4 * 4]);
                As[(c4 * 4 + 0) * APAD + r] = v.x;
                As[(c4 * 4 + 1) * APAD + r] = v.y;
                As[(c4 * 4 + 2) * APAD + r] = v.z;
                As[(c4 * 4 + 3) * APAD + r] = v.w;
            }
            // ---- stage B (32 f x 512 cols), 8 float4 per thread
            #pragma unroll
            for (int it = 0; it < 8; ++it) {
                int fi = it * 512 + tid;     // float4 index 0..4095
                int ff = fi >> 7;            // 0..31
                int c4 = fi & 127;           // float4 col 0..127
                int k  = c4 >> 6;
                int g4 = c4 & 63;
                const float* Wp = W + (size_t)k * FF * FF + (size_t)(f0 + ff) * FF + g4 * 4;
                float4 v = *reinterpret_cast<const float4*>(Wp);
                *reinterpret_cast<float4*>(&Bs[ff * 512 + c4 * 4]) = v;
            }
            __syncthreads();
            // ---- compute
            #pragma unroll 8
            for (int ff = 0; ff < BK; ++ff) {
                float4 a4 = *reinterpret_cast<const float4*>(&As[ff * APAD + ty * 4]);
                float av[4] = {a4.x, a4.y, a4.z, a4.w};
                #pragma unroll
                for (int j = 0; j < 4; ++j) {
                    float4 b4 = *reinterpret_cast<const float4*>(&Bs[ff * 512 + j * 128 + tx * 4]);
                    float bv[4] = {b4.x, b4.y, b4.z, b4.w};
                    #pragma unroll
                    for (int i = 0; i < 4; ++i)
                        #pragma unroll
                        for (int c = 0; c < 4; ++c)
                            acc[i][j][c] = fmaf(av[i], bv[c], acc[i][j][c]);
                }
            }
            __syncthreads();
        }
    }

    // ---- epilogue: pair quadrants (j, j+2) = (k0, k1) at same g
    #pragma unroll
    for (int i = 0; i < 4; ++i) {
        int grow = row0 + ty * 4 + i;
        if (grow >= NN) continue;
        #pragma unroll
        for (int jj = 0; jj < 2; ++jj) {
            int g = jj * 128 + tx * 4;
            float4 res;
            float* rp = &res.x;
            #pragma unroll
            for (int c = 0; c < 4; ++c) {
                float c0 = acc[i][jj][c]     + bias[g + c];
                float c1 = acc[i][jj + 2][c] + bias[256 + g + c];
                float arma = 0.5f * (fmaxf(c0, 0.f) + fmaxf(c1, 0.f));
                float xv = x[(size_t)grow * FF + g + c];
                rp[c] = xv + fmaxf(arma, 0.f);
            }
            *reinterpret_cast<float4*>(&out[(size_t)grow * FF + g]) = res;
        }
    }
}

extern "C" void kernel_launch(void* const* d_in, const int* in_sizes, int n_in,
                              void* d_out, int out_size, void* d_ws, size_t ws_size,
                              hipStream_t stream) {
    const float* x    = (const float*)d_in[0];
    const int*   ei   = (const int*)d_in[1];
    const float* wi   = (const float*)d_in[2];
    const float* wr   = (const float*)d_in[3];
    const float* bias = (const float*)d_in[4];
    float* out = (float*)d_out;

    float* deg  = (float*)d_ws;       // NN floats
    float* dinv = deg + NN;           // NN floats
    float* y    = out;                // reuse output buffer as aggregation scratch (51.2 MB)

    hipMemsetAsync(deg, 0, NN * sizeof(float), stream);
    hipMemsetAsync(y, 0, (size_t)NN * FF * sizeof(float), stream);

    k_deg<<<(NE + 255) / 256, 256, 0, stream>>>(ei, deg);
    k_dinv<<<(NN + 255) / 256, 256, 0, stream>>>(deg, dinv);
    k_scatter<<<(NE * 64) / 256, 256, 0, stream>>>(ei, x, dinv, y);
    k_gemm<<<(NN + BM - 1) / BM, 512, 0, stream>>>(x, y, wi, wr, bias, out);
}

// Round 2
// 579.000 us; speedup vs baseline: 2.5945x; 2.5945x over previous
//
#include <hip/hip_runtime.h>

#define NN 50000
#define NE 320000
#define FF 256

#define BM 64
#define BK 32
#define APAD 68   // padded LDS row length (words) for transposed A tile; %4==0 for float4 reads

// ---------------- degree (int histogram over dst) ----------------
__global__ void k_deg(const int* __restrict__ ei, int* __restrict__ deg) {
    int e = blockIdx.x * blockDim.x + threadIdx.x;
    if (e < NE) atomicAdd(&deg[ei[NE + e]], 1);
}

__global__ void k_dinv(const int* __restrict__ deg, float* __restrict__ dinv) {
    int n = blockIdx.x * blockDim.x + threadIdx.x;
    if (n < NN) {
        int d = deg[n];
        dinv[n] = d > 0 ? rsqrtf((float)d) : 0.f;
    }
}

// ---------------- exclusive scan of deg -> off, cur (single block) ----------------
__global__ __launch_bounds__(1024)
void k_scan(const int* __restrict__ deg, int* __restrict__ off, int* __restrict__ cur) {
    __shared__ int s[1024];
    __shared__ int carry_s;
    if (threadIdx.x == 0) carry_s = 0;
    __syncthreads();
    for (int base = 0; base < NN; base += 1024) {
        int i = base + threadIdx.x;
        int v = (i < NN) ? deg[i] : 0;
        s[threadIdx.x] = v;
        __syncthreads();
        #pragma unroll
        for (int d = 1; d < 1024; d <<= 1) {
            int t = (threadIdx.x >= d) ? s[threadIdx.x - d] : 0;
            __syncthreads();
            s[threadIdx.x] += t;
            __syncthreads();
        }
        int excl = carry_s + s[threadIdx.x] - v;
        if (i < NN) { off[i] = excl; cur[i] = excl; }
        __syncthreads();
        if (threadIdx.x == 1023) carry_s += s[1023];
        __syncthreads();
    }
}

// ---------------- CSR fill: csr_src[pos] = src, grouped by dst ----------------
__global__ void k_fill(const int* __restrict__ ei, int* __restrict__ cur,
                       int* __restrict__ csr_src) {
    int e = blockIdx.x * blockDim.x + threadIdx.x;
    if (e < NE) {
        int dst = ei[NE + e];
        int pos = atomicAdd(&cur[dst], 1);
        csr_src[pos] = ei[e];
    }
}

// ---------------- aggregation: one wave per node, no atomics ----------------
// y[n,:] = sum_{e: dst=n} dinv[src]*dinv[n] * x[src,:]
__global__ __launch_bounds__(256)
void k_agg(const int* __restrict__ off, const int* __restrict__ deg,
           const int* __restrict__ csr_src, const float* __restrict__ dinv,
           const float* __restrict__ x, float* __restrict__ y) {
    int wid = (blockIdx.x * blockDim.x + threadIdx.x) >> 6;
    if (wid >= NN) return;
    int lane = threadIdx.x & 63;
    int start = off[wid];
    int d = deg[wid];
    float di = dinv[wid];
    float4 acc = make_float4(0.f, 0.f, 0.f, 0.f);
    for (int e = 0; e < d; ++e) {
        int src = csr_src[start + e];
        float w = di * dinv[src];
        float4 v = *reinterpret_cast<const float4*>(&x[(size_t)src * FF + lane * 4]);
        acc.x = fmaf(w, v.x, acc.x);
        acc.y = fmaf(w, v.y, acc.y);
        acc.z = fmaf(w, v.z, acc.z);
        acc.w = fmaf(w, v.w, acc.w);
    }
    *reinterpret_cast<float4*>(&y[(size_t)wid * FF + lane * 4]) = acc;
}

// ---------------- fused GEMM + epilogue (unchanged from R1) ----------------
__global__ __launch_bounds__(512, 4)
void k_gemm(const float* __restrict__ x, const float* __restrict__ y,
            const float* __restrict__ wi, const float* __restrict__ wr,
            const float* __restrict__ bias, float* __restrict__ out) {
    __shared__ float As[BK * APAD];   // transposed: As[f][row]
    __shared__ float Bs[BK * 512];    // Bs[f][col], col = k*256+g

    const int tid = threadIdx.x;
    const int tx = tid & 31;          // 32 col groups
    const int ty = tid >> 5;          // 16 row groups
    const int row0 = blockIdx.x * BM;

    float acc[4][4][4];               // [row i][quadrant j][c] ; col = j*128 + tx*4 + c
    #pragma unroll
    for (int i = 0; i < 4; ++i)
        #pragma unroll
        for (int j = 0; j < 4; ++j)
            #pragma unroll
            for (int c = 0; c < 4; ++c) acc[i][j][c] = 0.f;

    for (int p = 0; p < 2; ++p) {
        const float* A = p ? x : y;
        const float* W = p ? wr : wi;
        for (int f0 = 0; f0 < FF; f0 += BK) {
            // ---- stage A (64 rows x 32 f), one float4 per thread, store transposed
            {
                int r  = tid >> 3;       // 0..63
                int c4 = tid & 7;        // 0..7
                int grow = row0 + r;
                float4 v = make_float4(0.f, 0.f, 0.f, 0.f);
                if (grow < NN)
                    v = *reinterpret_cast<const float4*>(&A[(size_t)grow * FF + f0 + c4 * 4]);
                As[(c4 * 4 + 0) * APAD + r] = v.x;
                As[(c4 * 4 + 1) * APAD + r] = v.y;
                As[(c4 * 4 + 2) * APAD + r] = v.z;
                As[(c4 * 4 + 3) * APAD + r] = v.w;
            }
            // ---- stage B (32 f x 512 cols), 8 float4 per thread
            #pragma unroll
            for (int it = 0; it < 8; ++it) {
                int fi = it * 512 + tid;     // float4 index 0..4095
                int ff = fi >> 7;            // 0..31
                int c4 = fi & 127;           // float4 col 0..127
                int k  = c4 >> 6;
                int g4 = c4 & 63;
                const float* Wp = W + (size_t)k * FF * FF + (size_t)(f0 + ff) * FF + g4 * 4;
                float4 v = *reinterpret_cast<const float4*>(Wp);
                *reinterpret_cast<float4*>(&Bs[ff * 512 + c4 * 4]) = v;
            }
            __syncthreads();
            // ---- compute
            #pragma unroll 8
            for (int ff = 0; ff < BK; ++ff) {
                float4 a4 = *reinterpret_cast<const float4*>(&As[ff * APAD + ty * 4]);
                float av[4] = {a4.x, a4.y, a4.z, a4.w};
                #pragma unroll
                for (int j = 0; j < 4; ++j) {
                    float4 b4 = *reinterpret_cast<const float4*>(&Bs[ff * 512 + j * 128 + tx * 4]);
                    float bv[4] = {b4.x, b4.y, b4.z, b4.w};
                    #pragma unroll
                    for (int i = 0; i < 4; ++i)
                        #pragma unroll
                        for (int c = 0; c < 4; ++c)
                            acc[i][j][c] = fmaf(av[i], bv[c], acc[i][j][c]);
                }
            }
            __syncthreads();
        }
    }

    // ---- epilogue: pair quadrants (j, j+2) = (k0, k1) at same g
    #pragma unroll
    for (int i = 0; i < 4; ++i) {
        int grow = row0 + ty * 4 + i;
        if (grow >= NN) continue;
        #pragma unroll
        for (int jj = 0; jj < 2; ++jj) {
            int g = jj * 128 + tx * 4;
            float4 res;
            float* rp = &res.x;
            #pragma unroll
            for (int c = 0; c < 4; ++c) {
                float c0 = acc[i][jj][c]     + bias[g + c];
                float c1 = acc[i][jj + 2][c] + bias[256 + g + c];
                float arma = 0.5f * (fmaxf(c0, 0.f) + fmaxf(c1, 0.f));
                float xv = x[(size_t)grow * FF + g + c];
                rp[c] = xv + fmaxf(arma, 0.f);
            }
            *reinterpret_cast<float4*>(&out[(size_t)grow * FF + g]) = res;
        }
    }
}

extern "C" void kernel_launch(void* const* d_in, const int* in_sizes, int n_in,
                              void* d_out, int out_size, void* d_ws, size_t ws_size,
                              hipStream_t stream) {
    const float* x    = (const float*)d_in[0];
    const int*   ei   = (const int*)d_in[1];
    const float* wi   = (const float*)d_in[2];
    const float* wr   = (const float*)d_in[3];
    const float* bias = (const float*)d_in[4];
    float* out = (float*)d_out;

    // workspace layout (ints/floats, ~2.1 MB total)
    int*   deg     = (int*)d_ws;            // NN
    int*   off     = deg + NN;              // NN
    int*   cur     = off + NN;              // NN
    int*   csr_src = cur + NN;              // NE
    float* dinv    = (float*)(csr_src + NE);// NN
    float* y       = out;                   // reuse output buffer as aggregation target

    hipMemsetAsync(deg, 0, NN * sizeof(int), stream);

    k_deg <<<(NE + 255) / 256, 256, 0, stream>>>(ei, deg);
    k_dinv<<<(NN + 255) / 256, 256, 0, stream>>>(deg, dinv);
    k_scan<<<1, 1024, 0, stream>>>(deg, off, cur);
    k_fill<<<(NE + 255) / 256, 256, 0, stream>>>(ei, cur, csr_src);
    k_agg <<<(NN * 64 + 255) / 256, 256, 0, stream>>>(off, deg, csr_src, dinv, x, y);
    k_gemm<<<(NN + BM - 1) / BM, 512, 0, stream>>>(x, y, wi, wr, bias, out);
}

// Round 3
// 289.887 us; speedup vs baseline: 5.1821x; 1.9973x over previous
//
#include <hip/hip_runtime.h>

#define NN 50000
#define NE 320000
#define FF 256

typedef short short8 __attribute__((ext_vector_type(8)));
typedef float f32x4 __attribute__((ext_vector_type(4)));
typedef unsigned short us4 __attribute__((ext_vector_type(4)));

static __device__ __forceinline__ unsigned short f2bf(float f) {
    union { float f; unsigned u; } v; v.f = f;
    unsigned r = v.u + 0x7FFFu + ((v.u >> 16) & 1u);   // RNE
    return (unsigned short)(r >> 16);
}

// ---------------- degree (int histogram over dst) ----------------
__global__ void k_deg(const int* __restrict__ ei, int* __restrict__ deg) {
    int e = blockIdx.x * blockDim.x + threadIdx.x;
    if (e < NE) atomicAdd(&deg[ei[NE + e]], 1);
}

__global__ void k_dinv(const int* __restrict__ deg, float* __restrict__ dinv) {
    int n = blockIdx.x * blockDim.x + threadIdx.x;
    if (n < NN) {
        int d = deg[n];
        dinv[n] = d > 0 ? rsqrtf((float)d) : 0.f;
    }
}

// ---------------- exclusive scan of deg -> off, cur (single block) ----------------
__global__ __launch_bounds__(1024)
void k_scan(const int* __restrict__ deg, int* __restrict__ off, int* __restrict__ cur) {
    __shared__ int s[1024];
    __shared__ int carry_s;
    if (threadIdx.x == 0) carry_s = 0;
    __syncthreads();
    for (int base = 0; base < NN; base += 1024) {
        int i = base + threadIdx.x;
        int v = (i < NN) ? deg[i] : 0;
        s[threadIdx.x] = v;
        __syncthreads();
        #pragma unroll
        for (int d = 1; d < 1024; d <<= 1) {
            int t = (threadIdx.x >= d) ? s[threadIdx.x - d] : 0;
            __syncthreads();
            s[threadIdx.x] += t;
            __syncthreads();
        }
        int excl = carry_s + s[threadIdx.x] - v;
        if (i < NN) { off[i] = excl; cur[i] = excl; }
        __syncthreads();
        if (threadIdx.x == 1023) carry_s += s[1023];
        __syncthreads();
    }
}

// ---------------- CSR fill ----------------
__global__ void k_fill(const int* __restrict__ ei, int* __restrict__ cur,
                       int* __restrict__ csr_src) {
    int e = blockIdx.x * blockDim.x + threadIdx.x;
    if (e < NE) {
        int dst = ei[NE + e];
        int pos = atomicAdd(&cur[dst], 1);
        csr_src[pos] = ei[e];
    }
}

// ---------------- aggregation: one wave per node, write bf16 y-half of Ab ----------------
__global__ __launch_bounds__(256)
void k_agg(const int* __restrict__ off, const int* __restrict__ deg,
           const int* __restrict__ csr_src, const float* __restrict__ dinv,
           const float* __restrict__ x, unsigned short* __restrict__ Ab) {
    int wid = (blockIdx.x * blockDim.x + threadIdx.x) >> 6;
    if (wid >= NN) return;
    int lane = threadIdx.x & 63;
    int start = off[wid];
    int d = deg[wid];
    float di = dinv[wid];
    float4 acc = make_float4(0.f, 0.f, 0.f, 0.f);
    for (int e = 0; e < d; ++e) {
        int src = csr_src[start + e];
        float wgt = di * dinv[src];
        float4 v = *reinterpret_cast<const float4*>(&x[(size_t)src * FF + lane * 4]);
        acc.x = fmaf(wgt, v.x, acc.x);
        acc.y = fmaf(wgt, v.y, acc.y);
        acc.z = fmaf(wgt, v.z, acc.z);
        acc.w = fmaf(wgt, v.w, acc.w);
    }
    us4 o = {f2bf(acc.x), f2bf(acc.y), f2bf(acc.z), f2bf(acc.w)};
    *reinterpret_cast<us4*>(Ab + (size_t)wid * 512 + lane * 4) = o;
}

// ---------------- x -> bf16 x-half of Ab (cols 256..511) ----------------
__global__ void k_xcvt(const float* __restrict__ x, unsigned short* __restrict__ Ab) {
    int t = blockIdx.x * blockDim.x + threadIdx.x;
    if (t >= NN * 64) return;
    int n = t >> 6, q = t & 63;
    float4 v = *reinterpret_cast<const float4*>(&x[(size_t)n * FF + q * 4]);
    us4 o = {f2bf(v.x), f2bf(v.y), f2bf(v.z), f2bf(v.w)};
    *reinterpret_cast<us4*>(Ab + (size_t)n * 512 + 256 + q * 4) = o;
}

// ---------------- B prep: fragment-linear bf16 Bp [kc 0..15][cf 0..31][lane][8] ----------------
// col = cf*16 + (lane&15); K = kc*32 + (lane>>4)*8 + e
// B[K][col]: kpart = col>>8, g = col&255, f = K&255, src = (K<256 ? wi : wr)[kpart][f][g]
__global__ void k_bprep(const float* __restrict__ wi, const float* __restrict__ wr,
                        unsigned short* __restrict__ Bp) {
    int t = blockIdx.x * blockDim.x + threadIdx.x;   // 0..32767
    int l = t & 63;
    int fb = t >> 6;          // 0..511
    int kc = fb >> 5;
    int cf = fb & 31;
    int col = cf * 16 + (l & 15);
    int kpart = col >> 8;
    int g = col & 255;
    int K0 = kc * 32 + (l >> 4) * 8;
    unsigned short* dst = Bp + (size_t)fb * 512 + (size_t)l * 8;
    #pragma unroll
    for (int e = 0; e < 8; ++e) {
        int K = K0 + e;
        const float* srcp = (K < 256) ? wi : wr;
        float v = srcp[(size_t)kpart * 65536 + (size_t)(K & 255) * 256 + g];
        dst[e] = f2bf(v);
    }
}

// ---------------- MFMA GEMM + epilogue, no LDS ----------------
// Block: 64 rows, 4 waves; wave w covers cols g in [w*64, w*64+64) for both k=0 and k=1.
__global__ __launch_bounds__(256, 2)
void k_mm(const unsigned short* __restrict__ Ab, const unsigned short* __restrict__ Bp,
          const float* __restrict__ x, const float* __restrict__ bias,
          float* __restrict__ out) {
    const int l = threadIdx.x & 63;
    const int w = threadIdx.x >> 6;
    const int row0 = blockIdx.x * 64;
    const int rA = l & 15;
    const int kA = (l >> 4) * 8;

    f32x4 acc[4][8];
    #pragma unroll
    for (int i = 0; i < 4; ++i)
        #pragma unroll
        for (int j = 0; j < 8; ++j) acc[i][j] = (f32x4){0.f, 0.f, 0.f, 0.f};

    const unsigned short* ap[4];
    #pragma unroll
    for (int rf = 0; rf < 4; ++rf) {
        int r = row0 + rf * 16 + rA;
        if (r >= NN) r = NN - 1;                  // clamp tail rows (stores masked below)
        ap[rf] = Ab + (size_t)r * 512 + kA;
    }
    const unsigned short* bp = Bp + (size_t)l * 8;

    for (int kc = 0; kc < 16; ++kc) {
        short8 a[4], b[8];
        #pragma unroll
        for (int rf = 0; rf < 4; ++rf)
            a[rf] = *reinterpret_cast<const short8*>(ap[rf] + kc * 32);
        #pragma unroll
        for (int c = 0; c < 8; ++c) {
            int cf = (c < 4) ? (w * 4 + c) : (12 + w * 4 + c);   // c>=4 -> 16 + w*4 + (c-4)
            b[c] = *reinterpret_cast<const short8*>(bp + (size_t)(kc * 32 + cf) * 512);
        }
        #pragma unroll
        for (int rf = 0; rf < 4; ++rf)
            #pragma unroll
            for (int c = 0; c < 8; ++c)
                acc[rf][c] = __builtin_amdgcn_mfma_f32_16x16x32_bf16(a[rf], b[c], acc[rf][c], 0, 0, 0);
    }

    __syncthreads();   // Ab aliases out: all waves' A reads must finish before stores

    #pragma unroll
    for (int rf = 0; rf < 4; ++rf) {
        const int rb = row0 + rf * 16 + (l >> 4) * 4;
        #pragma unroll
        for (int c = 0; c < 4; ++c) {
            const int gg = w * 64 + c * 16 + (l & 15);
            const float b0 = bias[gg], b1 = bias[256 + gg];
            #pragma unroll
            for (int j = 0; j < 4; ++j) {
                int r = rb + j;
                if (r < NN) {
                    float c0 = acc[rf][c][j] + b0;
                    float c1 = acc[rf][c + 4][j] + b1;
                    float arma = 0.5f * (fmaxf(c0, 0.f) + fmaxf(c1, 0.f));
                    out[(size_t)r * FF + gg] = x[(size_t)r * FF + gg] + fmaxf(arma, 0.f);
                }
            }
        }
    }
}

extern "C" void kernel_launch(void* const* d_in, const int* in_sizes, int n_in,
                              void* d_out, int out_size, void* d_ws, size_t ws_size,
                              hipStream_t stream) {
    const float* x    = (const float*)d_in[0];
    const int*   ei   = (const int*)d_in[1];
    const float* wi   = (const float*)d_in[2];
    const float* wr   = (const float*)d_in[3];
    const float* bias = (const float*)d_in[4];
    float* out = (float*)d_out;

    // workspace (~2.6 MB)
    int*   deg     = (int*)d_ws;              // NN
    int*   off     = deg + NN;                // NN
    int*   cur     = off + NN;                // NN
    int*   csr_src = cur + NN;                // NE
    float* dinv    = (float*)(csr_src + NE);  // NN
    unsigned short* Bp = (unsigned short*)(dinv + NN);   // 512*512 bf16 = 512 KB
    unsigned short* Ab = (unsigned short*)d_out;         // 50000 x 512 bf16 == d_out bytes

    hipMemsetAsync(deg, 0, NN * sizeof(int), stream);

    k_deg  <<<(NE + 255) / 256, 256, 0, stream>>>(ei, deg);
    k_dinv <<<(NN + 255) / 256, 256, 0, stream>>>(deg, dinv);
    k_scan <<<1, 1024, 0, stream>>>(deg, off, cur);
    k_fill <<<(NE + 255) / 256, 256, 0, stream>>>(ei, cur, csr_src);
    k_bprep<<<128, 256, 0, stream>>>(wi, wr, Bp);
    k_agg  <<<(NN * 64 + 255) / 256, 256, 0, stream>>>(off, deg, csr_src, dinv, x, Ab);
    k_xcvt <<<(NN * 64 + 255) / 256, 256, 0, stream>>>(x, Ab);
    k_mm   <<<(NN + 63) / 64, 256, 0, stream>>>(Ab, Bp, x, bias, out);
}